// Round 3
// baseline (214.285 us; speedup 1.0000x reference)
//
#include <hip/hip_runtime.h>

// YOLO-v1 loss, S=14, B=2, C=20, NCH=30, Nb=4096.
// R3: wave-private 64-cell tiles, barrier-free. Stage pred then target through
// the same per-wave 7.68 KB LDS buffer via global_load_lds (coalesced 1024 B
// per wave-instr), wave-local s_waitcnt instead of __syncthreads.
// 30.7 KB LDS/block -> 5 blocks/CU = 20 waves/CU.

#define NB 4096
#define NCELL (NB * 14 * 14)               // 802816
#define CELLS_PER_WAVE 64
#define NTILES (NCELL / CELLS_PER_WAVE)    // 12544
#define WAVES_PER_BLOCK 4
#define NBLOCKS (NTILES / WAVES_PER_BLOCK) // 3136
#define TILE_FLOATS (CELLS_PER_WAVE * 30)  // 1920 floats = 7680 B per tensor

#define GLOBAL_AS __attribute__((address_space(1)))
#define LDS_AS    __attribute__((address_space(3)))

__device__ __forceinline__ void async16(const float* g, float* l) {
    __builtin_amdgcn_global_load_lds((const GLOBAL_AS void*)g, (LDS_AS void*)l,
                                     16, 0, 0);
}

__global__ __launch_bounds__(256, 5) void yolo_partial(
    const float* __restrict__ pred, const float* __restrict__ target,
    float* __restrict__ partial)
{
    __shared__ float buf[WAVES_PER_BLOCK][TILE_FLOATS];   // 30720 B

    const int lane = threadIdx.x & 63;
    const int wid  = threadIdx.x >> 6;
    const int tile = blockIdx.x * WAVES_PER_BLOCK + wid;
    float* wbuf = buf[wid];
    const size_t base = (size_t)tile * TILE_FLOATS;

    // ---- stage pred tile: 480 float4 = 7 full wave-rounds + 1 half round
#pragma unroll
    for (int r = 0; r < 7; ++r)
        async16(pred + base + (size_t)(r * 64 + lane) * 4, wbuf + (r * 64 + lane) * 4);
    if (lane < 32)
        async16(pred + base + (size_t)(448 + lane) * 4, wbuf + (448 + lane) * 4);
    __asm volatile("s_waitcnt vmcnt(0)" ::: "memory");

    float p[30];
    {
        const float2* s2 = (const float2*)(wbuf + lane * 30);
#pragma unroll
        for (int i = 0; i < 15; ++i) {
            float2 a = s2[i]; p[2 * i] = a.x; p[2 * i + 1] = a.y;
        }
    }
    // drain our ds_reads before the async DMA overwrites the buffer
    __asm volatile("s_waitcnt lgkmcnt(0)" ::: "memory");

    // ---- stage target tile into the same wave-private buffer
#pragma unroll
    for (int r = 0; r < 7; ++r)
        async16(target + base + (size_t)(r * 64 + lane) * 4, wbuf + (r * 64 + lane) * 4);
    if (lane < 32)
        async16(target + base + (size_t)(448 + lane) * 4, wbuf + (448 + lane) * 4);
    __asm volatile("s_waitcnt vmcnt(0)" ::: "memory");

    float t[10];
    float cls = 0.0f;
    {
        const float2* s2 = (const float2*)(wbuf + lane * 30);
#pragma unroll
        for (int i = 0; i < 5; ++i) {
            float2 a = s2[i]; t[2 * i] = a.x; t[2 * i + 1] = a.y;
        }
#pragma unroll
        for (int i = 5; i < 15; ++i) {   // channels 10..29: class diff
            float2 a = s2[i];
            float d0 = p[2 * i] - a.x, d1 = p[2 * i + 1] - a.y;
            cls += d0 * d0 + d1 * d1;
        }
    }

    float loss;
    {
        const float t4 = t[4];
        const bool obj = (t4 > 0.0f);

        float dn0 = p[4] - t[4];
        float dn1 = p[9] - t[9];
        float noobj_l = (t4 == 0.0f) ? (dn0 * dn0 + dn1 * dn1) : 0.0f;

        const float invS = 1.0f / 14.0f;
        float tcx = t[0] * invS, tcy = t[1] * invS;
        float tx1 = tcx - 0.5f * t[2], ty1 = tcy - 0.5f * t[3];
        float tx2 = tcx + 0.5f * t[2], ty2 = tcy + 0.5f * t[3];
        float area_t = (tx2 - tx1) * (ty2 - ty1);

        float iou[2];
#pragma unroll
        for (int b = 0; b < 2; ++b) {
            const float* pb = p + 5 * b;
            float cx = pb[0] * invS, cy = pb[1] * invS;
            float x1 = cx - 0.5f * pb[2], y1 = cy - 0.5f * pb[3];
            float x2 = cx + 0.5f * pb[2], y2 = cy + 0.5f * pb[3];
            float lx = fmaxf(x1, tx1), ly = fmaxf(y1, ty1);
            float rx = fminf(x2, tx2), ry = fminf(y2, ty2);
            float wx = fmaxf(rx - lx, 0.0f), wy = fmaxf(ry - ly, 0.0f);
            float inter = wx * wy;
            float area_p = (x2 - x1) * (y2 - y1);
            iou[b] = inter / (area_p + area_t - inter);
        }

        // jnp.argmax picks first max -> box 1 only on strict >
        int r = (iou[1] > iou[0]) ? 1 : 0;
        float max_iou = fmaxf(iou[0], iou[1]);

        float obj_l = 0.0f;
        if (obj) {
            const float* pr = p + 5 * r;
            const float* tr = t + 5 * r;
            float dx = pr[0] - tr[0], dy = pr[1] - tr[1];
            float lxy = dx * dx + dy * dy;
            float dw = sqrtf(pr[2]) - sqrtf(tr[2]);
            float dh = sqrtf(pr[3]) - sqrtf(tr[3]);
            float lwh = dw * dw + dh * dh;
            float dob = pr[4] - max_iou;
            float lob = dob * dob;
            obj_l = 5.0f * (lxy + lwh) + lob + cls;
        }
        loss = obj_l + 0.5f * noobj_l;
    }

    // wave-local shuffle reduce; one store per wave, no barriers
    float v = loss;
#pragma unroll
    for (int off = 32; off > 0; off >>= 1)
        v += __shfl_down(v, off, 64);
    if (lane == 0)
        partial[tile] = v;
}

__global__ __launch_bounds__(256) void yolo_finalize(
    const float* __restrict__ partial, float* __restrict__ out)
{
    double s = 0.0;
    for (int i = threadIdx.x; i < NTILES; i += 256)
        s += (double)partial[i];

    __shared__ double sh[256];
    sh[threadIdx.x] = s;
    __syncthreads();
#pragma unroll
    for (int step = 128; step > 0; step >>= 1) {
        if (threadIdx.x < step) sh[threadIdx.x] += sh[threadIdx.x + step];
        __syncthreads();
    }
    if (threadIdx.x == 0)
        out[0] = (float)(sh[0] / (double)NB);
}

extern "C" void kernel_launch(void* const* d_in, const int* in_sizes, int n_in,
                              void* d_out, int out_size, void* d_ws, size_t ws_size,
                              hipStream_t stream) {
    const float* pred = (const float*)d_in[0];
    const float* target = (const float*)d_in[1];
    float* out = (float*)d_out;
    float* partial = (float*)d_ws;   // NTILES floats = 49 KB scratch

    yolo_partial<<<NBLOCKS, 256, 0, stream>>>(pred, target, partial);
    yolo_finalize<<<1, 256, 0, stream>>>(partial, out);
}